// Round 5
// baseline (671.529 us; speedup 1.0000x reference)
//
#include <hip/hip_runtime.h>

#define THREADS 256

typedef __attribute__((ext_vector_type(8))) short short8;
typedef __attribute__((ext_vector_type(4))) float f32x4;

__device__ __forceinline__ unsigned short f2bf(float f) {
    unsigned u = __builtin_bit_cast(unsigned, f);
    return (unsigned short)((u + 0x7FFFu + ((u >> 16) & 1u)) >> 16);  // RNE
}
__device__ __forceinline__ float bf2f_lo(unsigned u) { return __builtin_bit_cast(float, u << 16); }
__device__ __forceinline__ float bf2f_hi(unsigned u) { return __builtin_bit_cast(float, u & 0xFFFF0000u); }

// ---------------- CSR build (XCD-partitioned hist + place) ----------------

__global__ void zero_kernel(int* __restrict__ p, int n) {
    int i = blockIdx.x * blockDim.x + threadIdx.x;
    if (i < n) p[i] = 0;
}

__global__ void hist_part_kernel(const int* __restrict__ row, int* __restrict__ cnt,
                                 int n_edges, int n_nodes) {
    int g = blockIdx.x & 7;
    int inst = blockIdx.x >> 3;
    int ninst = gridDim.x >> 3;
    int lo = (int)(((long long)g * n_nodes) >> 3);
    int hi = (int)(((long long)(g + 1) * n_nodes) >> 3);
    int e0 = (int)(((long long)inst * n_edges) / ninst);
    int e1 = (int)(((long long)(inst + 1) * n_edges) / ninst);
    for (int e = e0 + threadIdx.x; e < e1; e += THREADS) {
        int r = row[e];
        if (r >= lo && r < hi) atomicAdd(&cnt[r], 1);
    }
}

__global__ void scan1_kernel(const int* __restrict__ cnt, int* __restrict__ offs,
                             int* __restrict__ bsum, int n) {
    int tid = threadIdx.x;
    int base = blockIdx.x * 1024 + tid * 4;
    int v0 = 0, v1 = 0, v2 = 0, v3 = 0;
    if (base + 3 < n) {
        int4 v = *reinterpret_cast<const int4*>(cnt + base);
        v0 = v.x; v1 = v.y; v2 = v.z; v3 = v.w;
    } else {
        if (base + 0 < n) v0 = cnt[base + 0];
        if (base + 1 < n) v1 = cnt[base + 1];
        if (base + 2 < n) v2 = cnt[base + 2];
    }
    int ts = v0 + v1 + v2 + v3;
    int lane = tid & 63;
    int incl = ts;
    #pragma unroll
    for (int off = 1; off < 64; off <<= 1) {
        int t = __shfl_up(incl, off, 64);
        if (lane >= off) incl += t;
    }
    __shared__ int wsum[4];
    int w = tid >> 6;
    if (lane == 63) wsum[w] = incl;
    __syncthreads();
    int wo = 0;
    for (int i = 0; i < w; ++i) wo += wsum[i];
    int excl = wo + incl - ts;
    if (base + 0 < n) offs[base + 0] = excl;
    if (base + 1 < n) offs[base + 1] = excl + v0;
    if (base + 2 < n) offs[base + 2] = excl + v0 + v1;
    if (base + 3 < n) offs[base + 3] = excl + v0 + v1 + v2;
    if (tid == THREADS - 1) bsum[blockIdx.x] = wo + incl;
}

__global__ void scan2_kernel(int* __restrict__ bsum, int nb) {
    int tid = threadIdx.x;
    int base = tid * 4;
    int v0 = 0, v1 = 0, v2 = 0, v3 = 0;
    if (base + 0 < nb) v0 = bsum[base + 0];
    if (base + 1 < nb) v1 = bsum[base + 1];
    if (base + 2 < nb) v2 = bsum[base + 2];
    if (base + 3 < nb) v3 = bsum[base + 3];
    int ts = v0 + v1 + v2 + v3;
    int lane = tid & 63;
    int incl = ts;
    #pragma unroll
    for (int off = 1; off < 64; off <<= 1) {
        int t = __shfl_up(incl, off, 64);
        if (lane >= off) incl += t;
    }
    __shared__ int wsum[4];
    int w = tid >> 6;
    if (lane == 63) wsum[w] = incl;
    __syncthreads();
    int wo = 0;
    for (int i = 0; i < w; ++i) wo += wsum[i];
    int excl = wo + incl - ts;
    if (base + 0 < nb) bsum[base + 0] = excl;
    if (base + 1 < nb) bsum[base + 1] = excl + v0;
    if (base + 2 < nb) bsum[base + 2] = excl + v0 + v1;
    if (base + 3 < nb) bsum[base + 3] = excl + v0 + v1 + v2;
    if (tid == THREADS - 1) bsum[nb] = wo + incl;
}

__global__ void scan3_kernel(int* __restrict__ offs, const int* __restrict__ bsum,
                             int* __restrict__ cur, int n) {
    int i = blockIdx.x * blockDim.x + threadIdx.x;
    if (i < n) {
        int v = offs[i] + bsum[i >> 10];
        offs[i] = v;
        cur[i] = v;
    }
    if (i == 0) offs[n] = bsum[(n + 1023) >> 10];
}

__global__ void place_part_kernel(const int* __restrict__ row, const int* __restrict__ col,
                                  const float* __restrict__ val, int* __restrict__ cur,
                                  int2* __restrict__ pr, int n_edges, int n_nodes) {
    int g = blockIdx.x & 7;
    int inst = blockIdx.x >> 3;
    int ninst = gridDim.x >> 3;
    int lo = (int)(((long long)g * n_nodes) >> 3);
    int hi = (int)(((long long)(g + 1) * n_nodes) >> 3);
    int e0 = (int)(((long long)inst * n_edges) / ninst);
    int e1 = (int)(((long long)(inst + 1) * n_edges) / ninst);
    for (int e = e0 + threadIdx.x; e < e1; e += THREADS) {
        int r = row[e];
        if (r >= lo && r < hi) {
            int p = atomicAdd(&cur[r], 1);
            pr[p] = make_int2(col[e], __float_as_int(val[e]));
        }
    }
}

// ---------------- converts ----------------

__global__ void cvt_bf16_kernel(const float4* __restrict__ in, uint4* __restrict__ out, int n8) {
    int i = blockIdx.x * blockDim.x + threadIdx.x;
    if (i >= n8) return;
    float4 a = in[2 * i], b = in[2 * i + 1];
    uint4 o;
    o.x = (unsigned)f2bf(a.x) | ((unsigned)f2bf(a.y) << 16);
    o.y = (unsigned)f2bf(a.z) | ((unsigned)f2bf(a.w) << 16);
    o.z = (unsigned)f2bf(b.x) | ((unsigned)f2bf(b.y) << 16);
    o.w = (unsigned)f2bf(b.z) | ((unsigned)f2bf(b.w) << 16);
    out[i] = o;
}

// Pack W (f32 [256][256], row = out-feature) into MFMA B-fragment order:
// frag f = (k0i*16 + nt)*64 + lane holds 8 bf16 = W[nt*16 + (lane&15)][k0i*32 + 8*(lane>>4) .. +7]
__global__ void cvt_W_pack_kernel(const float* __restrict__ W, unsigned short* __restrict__ WbP) {
    int f = blockIdx.x * blockDim.x + threadIdx.x;
    if (f >= 8192) return;
    int l = f & 63, nt = (f >> 6) & 15, k0i = f >> 10;
    int r = nt * 16 + (l & 15);
    int koff = k0i * 32 + 8 * (l >> 4);
    const float4* s = reinterpret_cast<const float4*>(W + r * 256 + koff);
    float4 a = s[0], b = s[1];
    uint4 o;
    o.x = (unsigned)f2bf(a.x) | ((unsigned)f2bf(a.y) << 16);
    o.y = (unsigned)f2bf(a.z) | ((unsigned)f2bf(a.w) << 16);
    o.z = (unsigned)f2bf(b.x) | ((unsigned)f2bf(b.y) << 16);
    o.w = (unsigned)f2bf(b.z) | ((unsigned)f2bf(b.w) << 16);
    reinterpret_cast<uint4*>(WbP)[f] = o;
}

// ---------------- fused SpMM (reg accum) + MFMA GEMM ----------------
// Block = 64 nodes, 4 waves; wave w owns nodes [base+w*16, +16): gathers each
// node's agg row into 4 registers/lane, writes bf16 row to its wave-private
// LDS slab, then (no barrier) MFMAs its 16 rows against B-fragments streamed
// from L2-resident WbP. Writes go straight to out with bias.
__launch_bounds__(256)
__global__ void spmm_gemm_fused(const uint2* __restrict__ xb, const int* __restrict__ offs,
                                const int2* __restrict__ pr,
                                const unsigned short* __restrict__ WbP,
                                const float* __restrict__ bias,
                                float* __restrict__ out, int n_nodes) {
    __shared__ unsigned short As[64][264];  // 4 wave-private 16-row slabs
    int tid = threadIdx.x;
    int lane = tid & 63;
    int w = tid >> 6;

    int g = blockIdx.x & 7;
    int inst = blockIdx.x >> 3;
    int lo = (int)(((long long)g * n_nodes) >> 3);
    int hi = (int)(((long long)(g + 1) * n_nodes) >> 3);
    int base = lo + inst * 64;
    if (base >= hi) return;

    // ---- phase 1: per-node register SpMM ----
    for (int ni = 0; ni < 16; ++ni) {
        int node = base + w * 16 + ni;
        float a0 = 0.f, a1 = 0.f, a2 = 0.f, a3 = 0.f;
        if (node < hi) {
            int s = offs[node], e = offs[node + 1];
            int i = s;
            if (i < e && (i & 1)) {
                int2 p = pr[i];
                uint2 xv = xb[(size_t)p.x * 64 + lane];
                float v = __int_as_float(p.y);
                a0 = fmaf(v, bf2f_lo(xv.x), a0); a1 = fmaf(v, bf2f_hi(xv.x), a1);
                a2 = fmaf(v, bf2f_lo(xv.y), a2); a3 = fmaf(v, bf2f_hi(xv.y), a3);
                ++i;
            }
            for (; i + 8 <= e; i += 8) {
                int4 pa = *reinterpret_cast<const int4*>(pr + i);
                int4 pb = *reinterpret_cast<const int4*>(pr + i + 2);
                int4 pc = *reinterpret_cast<const int4*>(pr + i + 4);
                int4 pd = *reinterpret_cast<const int4*>(pr + i + 6);
                uint2 x0 = xb[(size_t)pa.x * 64 + lane];
                uint2 x1 = xb[(size_t)pa.z * 64 + lane];
                uint2 x2 = xb[(size_t)pb.x * 64 + lane];
                uint2 x3 = xb[(size_t)pb.z * 64 + lane];
                uint2 x4_ = xb[(size_t)pc.x * 64 + lane];
                uint2 x5 = xb[(size_t)pc.z * 64 + lane];
                uint2 x6 = xb[(size_t)pd.x * 64 + lane];
                uint2 x7 = xb[(size_t)pd.z * 64 + lane];
                float v0 = __int_as_float(pa.y), v1 = __int_as_float(pa.w);
                float v2 = __int_as_float(pb.y), v3 = __int_as_float(pb.w);
                float v4 = __int_as_float(pc.y), v5 = __int_as_float(pc.w);
                float v6 = __int_as_float(pd.y), v7 = __int_as_float(pd.w);
                a0 = fmaf(v0, bf2f_lo(x0.x), a0); a1 = fmaf(v0, bf2f_hi(x0.x), a1);
                a2 = fmaf(v0, bf2f_lo(x0.y), a2); a3 = fmaf(v0, bf2f_hi(x0.y), a3);
                a0 = fmaf(v1, bf2f_lo(x1.x), a0); a1 = fmaf(v1, bf2f_hi(x1.x), a1);
                a2 = fmaf(v1, bf2f_lo(x1.y), a2); a3 = fmaf(v1, bf2f_hi(x1.y), a3);
                a0 = fmaf(v2, bf2f_lo(x2.x), a0); a1 = fmaf(v2, bf2f_hi(x2.x), a1);
                a2 = fmaf(v2, bf2f_lo(x2.y), a2); a3 = fmaf(v2, bf2f_hi(x2.y), a3);
                a0 = fmaf(v3, bf2f_lo(x3.x), a0); a1 = fmaf(v3, bf2f_hi(x3.x), a1);
                a2 = fmaf(v3, bf2f_lo(x3.y), a2); a3 = fmaf(v3, bf2f_hi(x3.y), a3);
                a0 = fmaf(v4, bf2f_lo(x4_.x), a0); a1 = fmaf(v4, bf2f_hi(x4_.x), a1);
                a2 = fmaf(v4, bf2f_lo(x4_.y), a2); a3 = fmaf(v4, bf2f_hi(x4_.y), a3);
                a0 = fmaf(v5, bf2f_lo(x5.x), a0); a1 = fmaf(v5, bf2f_hi(x5.x), a1);
                a2 = fmaf(v5, bf2f_lo(x5.y), a2); a3 = fmaf(v5, bf2f_hi(x5.y), a3);
                a0 = fmaf(v6, bf2f_lo(x6.x), a0); a1 = fmaf(v6, bf2f_hi(x6.x), a1);
                a2 = fmaf(v6, bf2f_lo(x6.y), a2); a3 = fmaf(v6, bf2f_hi(x6.y), a3);
                a0 = fmaf(v7, bf2f_lo(x7.x), a0); a1 = fmaf(v7, bf2f_hi(x7.x), a1);
                a2 = fmaf(v7, bf2f_lo(x7.y), a2); a3 = fmaf(v7, bf2f_hi(x7.y), a3);
            }
            for (; i + 2 <= e; i += 2) {
                int4 pa = *reinterpret_cast<const int4*>(pr + i);
                uint2 x0 = xb[(size_t)pa.x * 64 + lane];
                uint2 x1 = xb[(size_t)pa.z * 64 + lane];
                float v0 = __int_as_float(pa.y), v1 = __int_as_float(pa.w);
                a0 = fmaf(v0, bf2f_lo(x0.x), a0); a1 = fmaf(v0, bf2f_hi(x0.x), a1);
                a2 = fmaf(v0, bf2f_lo(x0.y), a2); a3 = fmaf(v0, bf2f_hi(x0.y), a3);
                a0 = fmaf(v1, bf2f_lo(x1.x), a0); a1 = fmaf(v1, bf2f_hi(x1.x), a1);
                a2 = fmaf(v1, bf2f_lo(x1.y), a2); a3 = fmaf(v1, bf2f_hi(x1.y), a3);
            }
            for (; i < e; ++i) {
                int2 p = pr[i];
                uint2 xv = xb[(size_t)p.x * 64 + lane];
                float v = __int_as_float(p.y);
                a0 = fmaf(v, bf2f_lo(xv.x), a0); a1 = fmaf(v, bf2f_hi(xv.x), a1);
                a2 = fmaf(v, bf2f_lo(xv.y), a2); a3 = fmaf(v, bf2f_hi(xv.y), a3);
            }
        }
        ushort4 o;
        o.x = f2bf(a0); o.y = f2bf(a1); o.z = f2bf(a2); o.w = f2bf(a3);
        *reinterpret_cast<ushort4*>(&As[w * 16 + ni][4 * lane]) = o;
    }

    // ---- phase 2: MFMA against streamed B-fragments (wave-private A rows) ----
    int lr = lane & 15, lg = lane >> 4;
    f32x4 acc[16];
    #pragma unroll
    for (int nt = 0; nt < 16; ++nt) acc[nt] = (f32x4){0.f, 0.f, 0.f, 0.f};

    for (int k0i = 0; k0i < 8; ++k0i) {
        short8 af = *reinterpret_cast<const short8*>(&As[w * 16 + lr][k0i * 32 + 8 * lg]);
        #pragma unroll
        for (int nt = 0; nt < 16; ++nt) {
            short8 bf_ = *reinterpret_cast<const short8*>(
                &WbP[(size_t)((k0i * 16 + nt) * 64 + lane) * 8]);
            acc[nt] = __builtin_amdgcn_mfma_f32_16x16x32_bf16(af, bf_, acc[nt], 0, 0, 0);
        }
    }

    int row0 = base + w * 16;
    #pragma unroll
    for (int nt = 0; nt < 16; ++nt) {
        int gc = nt * 16 + lr;
        float bv = bias[gc];
        #pragma unroll
        for (int q = 0; q < 4; ++q) {
            int gr = row0 + lg * 4 + q;
            if (gr < hi) out[(size_t)gr * 256 + gc] = acc[nt][q] + bv;
        }
    }
}

// ---------------- f32 fallback path (small ws) ----------------

__global__ void spmm_f32_kernel(const float4* __restrict__ x4, const int* __restrict__ offs,
                                const int2* __restrict__ pr, float4* __restrict__ out4,
                                int nnodes) {
    int wid = (blockIdx.x * blockDim.x + threadIdx.x) >> 6;
    int lane = threadIdx.x & 63;
    if (wid >= nnodes) return;
    int s = offs[wid], e = offs[wid + 1];
    float4 acc = make_float4(0.f, 0.f, 0.f, 0.f);
    for (int i = s; i < e; ++i) {
        int2 p = pr[i];
        float4 xv = x4[(size_t)p.x * 64 + lane];
        float v = __int_as_float(p.y);
        acc.x = fmaf(v, xv.x, acc.x); acc.y = fmaf(v, xv.y, acc.y);
        acc.z = fmaf(v, xv.z, acc.z); acc.w = fmaf(v, xv.w, acc.w);
    }
    out4[(size_t)wid * 64 + lane] = acc;
}

__launch_bounds__(256, 2)
__global__ void gemm_mfma_kernel(float* __restrict__ out, const unsigned short* __restrict__ Wb,
                                 const float* __restrict__ bias, int nrows) {
    __shared__ unsigned short As[64][264];
    __shared__ unsigned short Ws[256][40];
    int tid = threadIdx.x;
    int rowBase = blockIdx.x * 64;

    const float4* o4 = reinterpret_cast<const float4*>(out);
    for (int it = tid; it < 64 * 64; it += 256) {
        int r = it >> 6, c = it & 63;
        float4 v = make_float4(0.f, 0.f, 0.f, 0.f);
        int gr = rowBase + r;
        if (gr < nrows) v = o4[(size_t)gr * 64 + c];
        ushort4 w;
        w.x = f2bf(v.x); w.y = f2bf(v.y); w.z = f2bf(v.z); w.w = f2bf(v.w);
        *reinterpret_cast<ushort4*>(&As[r][c * 4]) = w;
    }

    int w = tid >> 6, lane = tid & 63;
    int lr = lane & 15, lg = lane >> 4;
    f32x4 acc[16];
    #pragma unroll
    for (int nt = 0; nt < 16; ++nt) acc[nt] = (f32x4){0.f, 0.f, 0.f, 0.f};

    for (int k0 = 0; k0 < 256; k0 += 32) {
        __syncthreads();
        for (int it = tid; it < 1024; it += 256) {
            int r = it >> 2, c = it & 3;
            uint4 v = *reinterpret_cast<const uint4*>(Wb + (size_t)r * 256 + k0 + c * 8);
            *reinterpret_cast<uint4*>(&Ws[r][c * 8]) = v;
        }
        __syncthreads();
        short8 af = *reinterpret_cast<const short8*>(&As[w * 16 + lr][k0 + 8 * lg]);
        #pragma unroll
        for (int nt = 0; nt < 16; ++nt) {
            short8 bf_ = *reinterpret_cast<const short8*>(&Ws[nt * 16 + lr][8 * lg]);
            acc[nt] = __builtin_amdgcn_mfma_f32_16x16x32_bf16(af, bf_, acc[nt], 0, 0, 0);
        }
    }

    #pragma unroll
    for (int nt = 0; nt < 16; ++nt) {
        int gc = nt * 16 + lr;
        float bv = bias[gc];
        #pragma unroll
        for (int q = 0; q < 4; ++q) {
            int gr = rowBase + w * 16 + lg * 4 + q;
            if (gr < nrows) out[(size_t)gr * 256 + gc] = acc[nt][q] + bv;
        }
    }
}

// ---------------- launch ----------------

extern "C" void kernel_launch(void* const* d_in, const int* in_sizes, int n_in,
                              void* d_out, int out_size, void* d_ws, size_t ws_size,
                              hipStream_t stream) {
    const float* x     = (const float*)d_in[0];
    const int*   erow  = (const int*)d_in[1];
    const int*   ecol  = (const int*)d_in[2];
    const float* evalv = (const float*)d_in[3];
    const float* W     = (const float*)d_in[4];
    const float* bias  = (const float*)d_in[5];
    float* out = (float*)d_out;

    int n_nodes = in_sizes[0] / 256;
    int n_edges = in_sizes[1];
    int nb = (n_nodes + 1023) >> 10;

    // workspace: cnt | offs | cur | bsum | Wb | WbP | pr | xb
    size_t A = (size_t)((n_nodes + 63) & ~63);
    int* cnt   = (int*)d_ws;
    int* offs  = cnt + A;
    int* cur   = offs + A;
    int* bsum  = cur + A;
    int* wbase = bsum + (((size_t)nb + 64) & ~63ull);
    unsigned short* Wb  = (unsigned short*)wbase;           // 256*256 bf16 (fallback)
    unsigned short* WbP = Wb + 65536;                       // packed frags
    int2* pr   = (int2*)(WbP + 65536);
    unsigned short* xb = (unsigned short*)(pr + n_edges);
    size_t need_bf16 = (size_t)((char*)(xb + (size_t)n_nodes * 256) - (char*)d_ws);
    bool use_bf16 = ws_size >= need_bf16;

    zero_kernel<<<(n_nodes + THREADS - 1) / THREADS, THREADS, 0, stream>>>(cnt, n_nodes);
    hist_part_kernel<<<2048, THREADS, 0, stream>>>(erow, cnt, n_edges, n_nodes);
    scan1_kernel<<<nb, THREADS, 0, stream>>>(cnt, offs, bsum, n_nodes);
    scan2_kernel<<<1, THREADS, 0, stream>>>(bsum, nb);
    scan3_kernel<<<(n_nodes + THREADS - 1) / THREADS, THREADS, 0, stream>>>(offs, bsum, cur, n_nodes);
    place_part_kernel<<<2048, THREADS, 0, stream>>>(erow, ecol, evalv, cur, pr, n_edges, n_nodes);

    if (use_bf16) {
        cvt_W_pack_kernel<<<32, THREADS, 0, stream>>>(W, WbP);
        int n8 = n_nodes * 32;
        cvt_bf16_kernel<<<(n8 + THREADS - 1) / THREADS, THREADS, 0, stream>>>(
            (const float4*)x, (uint4*)xb, n8);
        int max_grp = (n_nodes + 7) / 8;
        int bpg = (max_grp + 63) / 64;
        spmm_gemm_fused<<<8 * bpg, THREADS, 0, stream>>>(
            (const uint2*)xb, offs, pr, WbP, bias, out, n_nodes);
    } else {
        cvt_bf16_kernel<<<32, THREADS, 0, stream>>>((const float4*)W, (uint4*)Wb, 65536 / 8);
        int spmm_blocks = (n_nodes + 3) / 4;
        spmm_f32_kernel<<<spmm_blocks, THREADS, 0, stream>>>(
            (const float4*)x, offs, pr, (float4*)out, n_nodes);
        int gemm_blocks = (n_nodes + 63) / 64;
        gemm_mfma_kernel<<<gemm_blocks, THREADS, 0, stream>>>(out, Wb, bias, n_nodes);
    }
}